// Round 19
// baseline (84.138 us; speedup 1.0000x reference)
//
#include <hip/hip_runtime.h>
#include <hip/hip_bf16.h>
#include <math.h>

// Transformer-XL relative multi-head attention, bf16 MFMA implementation.
// B=4, S=1024, H=16, Dh=32, DIM=512.
//
// relative_shift identity: shifted[q,k] = qv[q]·pA[m] + qv[q+1]·pB[m],
// m = k - q + S - 1;  pA[m]=Z[S+1+m], pB[m]=Z[m] with a single zero-padded
// tensor Z (rows [S+1, 2S+1) = p, all else 0).
//
// Round 19: gemm mode-0 widened to BN=256 (NR=8 n-frags/wave, grid 512).
// Per-iteration compute doubles while the per-iteration barrier/stall stays
// fixed — halves the structural stall per FLOP (gemm0 was at ~2.5x its
// memory/MFMA roofline from the 8-iteration K-loop's barrier tax).
// B fragments loaded per-n in the inner loop to cap VGPR (~112). z=2 V^T
// LDS-transpose epilogue generalized to BN=256 (trans [256][64]).
// Mode 1 (outproj) stays BN=128. attn (R16) and conv (R18) unchanged.

typedef float f32x4 __attribute__((ext_vector_type(4)));
typedef __bf16 bf16x8 __attribute__((ext_vector_type(8)));
typedef __bf16 bf16x2 __attribute__((ext_vector_type(2)));

#define MFMA16(a, b, c) __builtin_amdgcn_mfma_f32_16x16x32_bf16((a), (b), (c), 0, 0, 0)

constexpr int Bb  = 4;
constexpr int S   = 1024;
constexpr int H   = 16;
constexpr int Dh  = 32;
constexpr int DIM = 512;
// 1/sqrt(32) * log2(e): scores come out pre-scaled for v_exp_f32 (=2^x).
constexpr float SCALEL2E = 0.25501818637084186f;
constexpr int ZROWS = 3 * S + 16;              // phZ rows per (b,h)

constexpr size_t XN = (size_t)Bb * S * DIM;   // elems per activation tensor
constexpr size_t WN = (size_t)DIM * DIM;      // elems per weight matrix

__device__ inline bf16x8 cvt8(const float* __restrict__ p) {
  f32x4 a = *(const f32x4*)p;
  f32x4 b = *(const f32x4*)(p + 4);
  bf16x8 r;
  r[0] = (__bf16)a[0]; r[1] = (__bf16)a[1]; r[2] = (__bf16)a[2]; r[3] = (__bf16)a[3];
  r[4] = (__bf16)b[0]; r[5] = (__bf16)b[1]; r[6] = (__bf16)b[2]; r[7] = (__bf16)b[3];
  return r;
}

__device__ inline float fexp2(float x) {
  float r;
  asm("v_exp_f32 %0, %1" : "=v"(r) : "v"(x));
  return r;
}

__device__ inline void gload_lds16(const __bf16* g, __bf16* l) {
  __builtin_amdgcn_global_load_lds(
      (const __attribute__((address_space(1))) unsigned int*)g,
      (__attribute__((address_space(3))) unsigned int*)l, 16, 0, 0);
}

// ---------------------------------------------------------------------------
// Kernel 0: f32 -> bf16 weight conversion (y=0..4) + phZ zero bands (y=5).
// ---------------------------------------------------------------------------
__global__ __launch_bounds__(256) void conv_kernel(
    const float* __restrict__ wq, const float* __restrict__ wk,
    const float* __restrict__ wv, const float* __restrict__ wp,
    const float* __restrict__ wo,
    __bf16* __restrict__ wb, __bf16* __restrict__ phZ)
{
  const int y = blockIdx.y;
  if (y == 5) {
    // zero only the bands the attn kernel ever reads as zeros:
    // rows [960,1032) and [2040,2104) per bh (p rows overwrite the overlap).
    const int e8 = blockIdx.x * 256 + threadIdx.x;   // grid.x = 136
    if (e8 < 64 * 136 * 4) {
      const int rowIdx = e8 >> 2, chunk = e8 & 3;
      const int bh = rowIdx / 136;
      const int rl = rowIdx - bh * 136;
      const int row = (rl < 72) ? (960 + rl) : (2040 + (rl - 72));
      bf16x8 zz = {};
      *(bf16x8*)(phZ + ((size_t)bh * ZROWS + row) * Dh + chunk * 8) = zz;
    }
    return;
  }
  const float* src = (y == 0) ? wq : (y == 1) ? wk : (y == 2) ? wv
                   : (y == 3) ? wp : wo;
  __bf16* dst = wb + (size_t)y * WN;
  const size_t i = ((size_t)blockIdx.x * 256 + threadIdx.x) * 8;
  if (i >= WN) return;
  *(bf16x8*)(dst + i) = cvt8(src + i);
}

// ---------------------------------------------------------------------------
// Kernel 1: tiled bf16 GEMM  C[M, N=512] = A @ B^T, K=512.
// BM=64 (MR=2), 4 waves, BK=64; B via global_load_lds(16B, XOR-swizzled
// source). MODE 0 (z=0..3 projections, grid 512, BN=256): A staged from the
// f32 activation inputs with inline cvt (reg-staging + swizzled
// ds_write_b128). MODE 1 (z=4 outproj, grid 256, BN=128): A = ctx bf16 via
// global_load_lds. z=2 writes k-interleaved V^T via LDS transpose.
// ---------------------------------------------------------------------------
template <int MODE>
__global__ __launch_bounds__(256) void gemm_kernel(
    const float* __restrict__ xq, const float* __restrict__ xk,
    const float* __restrict__ xv, const float* __restrict__ xp,
    const __bf16* __restrict__ wb, const __bf16* __restrict__ ctxp,
    const float* __restrict__ bq, const float* __restrict__ bk,
    const float* __restrict__ bv, const float* __restrict__ bo,
    const float* __restrict__ ub, const float* __restrict__ vb,
    __bf16* __restrict__ qu, __bf16* __restrict__ qv,
    __bf16* __restrict__ kk, __bf16* __restrict__ vt,
    __bf16* __restrict__ phZ,
    float* __restrict__ outp)
{
  constexpr int MR = 2;                       // m-frags per wave
  constexpr int BM = MR * 32;                 // 64-row block M-tile
  constexpr int NR = (MODE == 0) ? 8 : 4;     // n-frags per wave
  constexpr int BN = NR * 32;                 // 256 / 128 col block tile
  __shared__ __align__(16) __bf16 smem[BM * 64 + BN * 64];
  __bf16* As = smem;                 // [64 x 64]
  __bf16* Bs = smem + BM * 64;       // [BN x 64]
  __bf16* trans = smem;              // z=2 epilogue: [BN d][64 s]

  const int bid = blockIdx.x;
  const int u = bid >> 3;
  int bx, by, z;
  if (MODE == 0) {
    by = u & 1;
    const int idx = (bid & 7) + 8 * (u >> 1);
    bx = idx & 63; z = idx >> 6;
  } else {
    by = u & 3;
    const int idx = (bid & 7) + 8 * (u >> 2);
    bx = idx; z = 4;
  }

  const float* Axf = (z == 0) ? xq : (z == 1) ? xk : (z == 2) ? xv : xp;
  const __bf16* Bg = wb + (size_t)z * WN;

  const int tid = threadIdx.x;
  const int wid = tid >> 6;
  const int ln = tid & 63;
  const int lm = ln & 15, lg = ln >> 4;
  const int wr = wid >> 1, wc = wid & 1;
  const int brow = bx * BM;
  const int bcol = by * BN;

  const int srow = ln >> 3;
  const int sc   = ln & 7;

  f32x4 acc[MR][NR] = {};

  for (int kt = 0; kt < DIM / 64; ++kt) {
    const int k0 = kt * 64;
    if (MODE == 0) {
      // A: f32 -> bf16 reg-staging. Wave stages rows [wid*16, wid*16+16);
      // lane: row rl = wid*16 + (ln>>2), chunks (ln&3) and (ln&3)+4.
      const int rl = wid * 16 + (ln >> 2);
      const float* Af = Axf + (size_t)(brow + rl) * DIM + k0;
      const int c0_ = ln & 3;
      const int c1_ = c0_ + 4;
      *(bf16x8*)&As[rl * 64 + ((c0_ ^ (rl & 7)) * 8)] = cvt8(Af + c0_ * 8);
      *(bf16x8*)&As[rl * 64 + ((c1_ ^ (rl & 7)) * 8)] = cvt8(Af + c1_ * 8);
    } else {
#pragma unroll
      for (int i = 0; i < MR; ++i) {          // A: ctx bf16 via gload_lds
        const int rb = wid * (MR * 8) + i * 8;
        const int r = rb + srow;
        const int cg = sc ^ (r & 7);
        gload_lds16(ctxp + (size_t)(brow + r) * DIM + k0 + cg * 8,
                    &As[rb * 64]);
      }
    }
#pragma unroll
    for (int i = 0; i < NR; ++i) {            // B: BN rows via gload_lds
      const int rb = wid * (NR * 8) + i * 8;
      const int r = rb + srow;
      const int cg = sc ^ (r & 7);
      gload_lds16(Bg + (size_t)(bcol + r) * DIM + k0 + cg * 8, &Bs[rb * 64]);
    }
    __syncthreads();

#pragma unroll
    for (int ks = 0; ks < 2; ++ks) {
      bf16x8 a[MR];
#pragma unroll
      for (int m = 0; m < MR; ++m) {
        const int row = wr * (MR * 16) + m * 16 + lm;
        const int cc = (ks * 4 + lg) ^ (row & 7);
        a[m] = *(const bf16x8*)&As[row * 64 + cc * 8];
      }
#pragma unroll
      for (int n = 0; n < NR; ++n) {
        const int row = wc * (NR * 16) + n * 16 + lm;
        const int cc = (ks * 4 + lg) ^ (row & 7);
        bf16x8 bn = *(const bf16x8*)&Bs[row * 64 + cc * 8];
#pragma unroll
        for (int m = 0; m < MR; ++m)
          acc[m][n] = MFMA16(a[m], bn, acc[m][n]);
      }
    }
    __syncthreads();
  }

  // ---- epilogue
  if constexpr (MODE == 0) {
    if (z == 2) {
      // k-interleaved V^T via LDS transpose (MR=2 form). Each wave owns a
      // 32-s-block (rows wr*32..wr*32+31); pair (s, s+16) = (acc[0][n][r],
      // acc[1][n][r]) with t = lg*4+r -> slots (2t, 2t+1) at p = wr*32+2t.
      const int b = brow >> 10;
      const int sbase = brow & (S - 1);
#pragma unroll
      for (int n = 0; n < NR; ++n) {
        const int dl = wc * (NR * 16) + n * 16 + lm;   // 0..BN-1
        const float bias = bv[bcol + dl];
#pragma unroll
        for (int r = 0; r < 4; ++r) {
          const int p = wr * 32 + 2 * (lg * 4 + r);    // even slot
          bf16x2 pk;
          pk[0] = (__bf16)(acc[0][n][r] + bias);       // col s
          pk[1] = (__bf16)(acc[1][n][r] + bias);       // col s+16
          const int base = dl * 64 + (((p >> 3) ^ (dl & 7)) * 8) + (p & 7);
          *(bf16x2*)(trans + base) = pk;
        }
      }
      __syncthreads();
#pragma unroll
      for (int j = 0; j < BN / 64; ++j) {
        const int dl = (tid >> 2) + j * 64;            // 0..BN-1
        const int d = dl & 31, hl = dl >> 5;
        const int cp = (tid & 3) * 2;                  // chunk pair (16 elems)
        bf16x8 v0 = *(const bf16x8*)(trans + dl * 64 + ((cp ^ (dl & 7)) * 8));
        bf16x8 v1 = *(const bf16x8*)(trans + dl * 64 + (((cp + 1) ^ (dl & 7)) * 8));
        const int bh2 = b * H + (bcol >> 5) + hl;
        __bf16* dst = vt + ((size_t)bh2 * Dh + d) * S + sbase + cp * 8;
        *(bf16x8*)dst = v0;
        *(bf16x8*)(dst + 8) = v1;
      }
      return;
    }
  }

#pragma unroll
  for (int n = 0; n < NR; ++n) {
    const int o = bcol + wc * (NR * 16) + n * 16 + lm;
    float bias = 0.f, ubv = 0.f, vbv = 0.f;
    if (z == 0) { bias = bq[o]; ubv = ub[o]; vbv = vb[o]; }
    else if (z == 1) bias = bk[o];
    else if (z == 4) bias = bo[o];
    const int h = o >> 5, d = o & 31;
#pragma unroll
    for (int m = 0; m < MR; ++m) {
#pragma unroll
      for (int r = 0; r < 4; ++r) {
        const int M = brow + wr * (MR * 16) + m * 16 + lg * 4 + r;
        const float val = acc[m][n][r];
        if (z == 4) {
          outp[(size_t)M * DIM + o] = val + bias;
          continue;
        }
        const int b = M >> 10, s = M & (S - 1);
        const int bh = b * H + h;
        if (z == 0) {
          // 1/sqrt(Dh)*log2(e) folded in (scores feed v_exp_f32 directly).
          const size_t idx2 = ((size_t)bh * S + s) * Dh + d;
          qu[idx2] = (__bf16)((val + bias + ubv) * SCALEL2E);
          qv[idx2] = (__bf16)((val + bias + vbv) * SCALEL2E);
        } else if (z == 1) {
          kk[((size_t)bh * S + s) * Dh + d] = (__bf16)(val + bias);
        } else {
          // phZ rows [S+1, 2S+1) = p; zero bands pre-filled by conv.
          phZ[((size_t)bh * ZROWS + (S + 1 + s)) * Dh + d] = (__bf16)val;
        }
      }
    }
  }
}

// ---------------------------------------------------------------------------
// Kernel 2: fused attention (R16, unchanged). 256-thread blocks, 4 waves x
// 16 q-rows, grid 1024. K/V staged 2 64-k groups ahead in 4 LDS buffers with
// 2-way-free XOR swizzle s(row)=(row>>1)&3; Z windows register-reused (4
// loads/iter); ONE barrier per 64-k with counted vmcnt(3); per-half P
// buffers (packed b32 stores, k-interleaved V^T); setprio around MFMA;
// ones-MFMA row sums; max-free softmax (exp2); pos gather via __shfl.
// ---------------------------------------------------------------------------
__global__ __launch_bounds__(256, 4) void attn_kernel(
    const __bf16* __restrict__ qu, const __bf16* __restrict__ qv,
    const __bf16* __restrict__ kk, const __bf16* __restrict__ vt,
    const __bf16* __restrict__ phZ,
    __bf16* __restrict__ ctx)
{
  __shared__ __align__(16) __bf16 kv_lds[4][2][1024];  // [buf][K|V][32x32]
  __shared__ __align__(16) __bf16 at_all[4][2][16 * 40];

  const int tid = threadIdx.x;
  const int wid = tid >> 6;
  const int l = tid & 63;
  const int lm = l & 15, lg = l >> 4;

  const int bid = blockIdx.x;               // [0, 1024)
  const int bh = (bid & 7) + 8 * ((bid >> 3) & 7);  // bh resident on XCD bid&7
  const int q0 = (bid >> 6) * 64 + wid * 16;
  const int h = bh & (H - 1), b = bh >> 4;

  const __bf16* qub = qu + (size_t)bh * S * Dh;
  const __bf16* qvb = qv + (size_t)bh * S * Dh;
  const __bf16* kb  = kk + (size_t)bh * S * Dh;
  const __bf16* vtb = vt + (size_t)bh * Dh * S;
  const __bf16* pZb = phZ + (size_t)bh * ZROWS * Dh;
  const __bf16* pAb = pZb + (size_t)(S + 1) * Dh;   // pA[m] = Z[S+1+m]

  const bf16x8 au  = *(const bf16x8*)(qub + (size_t)(q0 + lm) * Dh + lg * 8);
  const bf16x8 avA = *(const bf16x8*)(qvb + (size_t)(q0 + lm) * Dh + lg * 8);
  // row q+1 for the pB term; one-past reads hit allocated memory and are
  // multiplied by pB rows that are exactly zero wherever consumed.
  const bf16x8 avB = *(const bf16x8*)(qvb + (size_t)(q0 + 1 + lm) * Dh + lg * 8);

  int  slr[4];
  bool prd[4];
#pragma unroll
  for (int r = 0; r < 4; ++r) {
    const int qr = lg * 4 + r;
    slr[r] = (l & 48) | ((lm - qr + 15) & 15);
    prd[r] = (lm <= qr);
  }

  bf16x8 ones8;
#pragma unroll
  for (int i = 0; i < 8; ++i) ones8[i] = (__bf16)1.0f;

  f32x4 cta = {0.f,0.f,0.f,0.f}, ctb = {0.f,0.f,0.f,0.f};
  f32x4 ls  = {0.f,0.f,0.f,0.f};
  const f32x4 zero4 = {0.f,0.f,0.f,0.f};

  // staging: lane l writes 16B at linear offset l*16 in its wave's 1KB
  // quadrant (rows srow=l>>2, storage chunk l&3). Source chunk inverse-
  // swizzled with s(row) = (row>>1)&3  ->  ((l&3) ^ ((l>>3)&3)).
  const int srow = l >> 2;
  const int scg  = ((l & 3) ^ ((l >> 3) & 3)) * 8;
  auto stage = [&](int kt, int buf) {
    const __bf16* src;
    if (wid == 0)      src = kb  + (size_t)(kt + srow) * Dh + scg;
    else if (wid == 1) src = kb  + (size_t)(kt + 16 + srow) * Dh + scg;
    else if (wid == 2) src = vtb + (size_t)srow * S + kt + scg;
    else               src = vtb + (size_t)(16 + srow) * S + kt + scg;
    gload_lds16(src, &kv_lds[buf][wid >> 1][(wid & 1) * 512]);
  };

  // read chunk, same swizzle: rows lm and lm+16 share s = (lm>>1)&3.
  const int cc = (lg ^ ((lm >> 1) & 3)) * 8;

  // Z-window tile load: window(ktc) tile at +off (16-row tile), base uB_.
  auto zld = [&](int ktc, int off, bool uB_) -> bf16x8 {
    const int mb = ktc - q0 + (S - 16);
    const __bf16* zb = uB_ ? pZb : pAb;
    return *(const bf16x8*)(zb + (size_t)(mb + off + lm) * Dh + lg * 8);
  };

  // One 32-k tile using a resident Z register set.
  auto half = [&](int kt, int tb, __bf16* at,
                  bf16x8 z0, bf16x8 z1, bf16x8 z2, bool uB_) {
    const __bf16* Ks = kv_lds[tb][0];
    const __bf16* Vs = kv_lds[tb][1];
    bf16x8 kf0 = *(const bf16x8*)(Ks + lm * 32 + cc);
    bf16x8 kf1 = *(const bf16x8*)(Ks + (lm + 16) * 32 + cc);
    __builtin_amdgcn_s_setprio(1);
    f32x4 c0 = MFMA16(au, kf0, zero4);
    f32x4 c1 = MFMA16(au, kf1, zero4);
    const bf16x8 av = uB_ ? avB : avA;
    f32x4 pt0 = MFMA16(av, z0, zero4);
    f32x4 pt1 = MFMA16(av, z1, zero4);
    f32x4 pt2 = MFMA16(av, z2, zero4);
    __builtin_amdgcn_s_setprio(0);
    if (uB_ && (kt < q0 + 16)) {  // diagonal band (once per wave): add pA term
      const int mb = kt - q0 + (S - 16);
      bf16x8 y0 = *(const bf16x8*)(pAb + (size_t)(mb + lm) * Dh + lg * 8);
      bf16x8 y1 = *(const bf16x8*)(pAb + (size_t)(mb + 16 + lm) * Dh + lg * 8);
      bf16x8 y2 = *(const bf16x8*)(pAb + (size_t)(mb + 32 + lm) * Dh + lg * 8);
      pt0 = MFMA16(avA, y0, pt0);
      pt1 = MFMA16(avA, y1, pt1);
      pt2 = MFMA16(avA, y2, pt2);
    }

#pragma unroll
    for (int r = 0; r < 4; ++r) {
      const float v0 = __shfl(pt0[r], slr[r], 64);
      const float v1 = __shfl(pt1[r], slr[r], 64);
      const float v2 = __shfl(pt2[r], slr[r], 64);
      const float s0 = c0[r] + (prd[r] ? v0 : v1);
      const float s1 = c1[r] + (prd[r] ? v1 : v2);
      bf16x2 pp;
      pp[0] = (__bf16)fexp2(s0);             // k-col kt+lm     -> slot 2*lm
      pp[1] = (__bf16)fexp2(s1);             // k-col kt+16+lm  -> slot 2*lm+1
      *(bf16x2*)(at + (lg * 4 + r) * 40 + 2 * lm) = pp;
    }

    bf16x8 af  = *(const bf16x8*)(at + lm * 40 + lg * 8);
    bf16x8 vf0 = *(const bf16x8*)(Vs + lm * 32 + cc);
    bf16x8 vf1 = *(const bf16x8*)(Vs + (lm + 16) * 32 + cc);
    __builtin_amdgcn_s_setprio(1);
    cta = MFMA16(af, vf0, cta);
    ctb = MFMA16(af, vf1, ctb);
    ls  = MFMA16(af, ones8, ls);
    __builtin_amdgcn_s_setprio(0);
  };

  __bf16* at0 = at_all[wid][0];
  __bf16* at1 = at_all[wid][1];

  // ---- prologue: Z(0) + stage tiles 0,1.
  bf16x8 zA0, zA1, zA2;
  bool uA = (0 > q0 - 31);
  zA0 = zld(0, 0, uA);
  zA1 = zld(0, 16, uA);
  zA2 = zld(0, 32, uA);
  stage(0, 0);
  stage(32, 1);
  asm volatile("s_waitcnt vmcnt(0)" ::: "memory");
  __builtin_amdgcn_s_barrier();

  for (int kt = 0; kt < S; kt += 64) {
    const int t = kt >> 5;
    // next-64k stages first (oldest in vmcnt order -> full-body slack)
    stage((kt + 64 < S) ? kt + 64 : kt, (t + 2) & 3);
    stage((kt + 96 < S) ? kt + 96 : kt, (t + 3) & 3);

    // zB window (kt+32): tile0 == zA window tile2 when bases match.
    const bool uB = ((kt + 32) > q0 - 31);
    bf16x8 zB0;
    if (uB == uA) zB0 = zA2;
    else          zB0 = zld(kt + 32, 0, uB);
    bf16x8 zB1 = zld(kt + 32, 16, uB);
    bf16x8 zB2 = zld(kt + 32, 32, uB);

    half(kt, t & 3, at0, zA0, zA1, zA2, uA);

    // zA' window (kt+64): tiles 16,32 loaded directly (first use next iter);
    // tile0 == zB2 when bases match (copied after half B).
    const int ktn = (kt + 64 < S) ? kt + 64 : (S - 32);
    const bool uAn = (ktn > q0 - 31);
    zA1 = zld(ktn, 16, uAn);
    zA2 = zld(ktn, 32, uAn);

    half(kt + 32, (t + 1) & 3, at1, zB0, zB1, zB2, uB);

    if (uAn == uB) zA0 = zB2;
    else           zA0 = zld(ktn, 0, uAn);
    uA = uAn;

    asm volatile("s_waitcnt vmcnt(3)" ::: "memory");
    __builtin_amdgcn_s_barrier();
  }

  // ---- normalize + store ctx (ls[r] = row sum, identical across lm lanes)
#pragma unroll
  for (int r = 0; r < 4; ++r) {
    const int s0 = q0 + lg * 4 + r;
    const float inv = 1.f / ls[r];
    __bf16* cp = ctx + ((size_t)b * S + s0) * DIM + h * Dh;
    cp[lm]      = (__bf16)(cta[r] * inv);
    cp[16 + lm] = (__bf16)(ctb[r] * inv);
  }
}

// ---------------------------------------------------------------------------
extern "C" void kernel_launch(void* const* d_in, const int* in_sizes, int n_in,
                              void* d_out, int out_size, void* d_ws, size_t ws_size,
                              hipStream_t stream) {
  const float* query = (const float*)d_in[0];
  const float* key   = (const float*)d_in[1];
  const float* value = (const float*)d_in[2];
  const float* pos   = (const float*)d_in[3];
  const float* Wq = (const float*)d_in[4];
  const float* bq = (const float*)d_in[5];
  const float* Wk = (const float*)d_in[6];
  const float* bk = (const float*)d_in[7];
  const float* Wv = (const float*)d_in[8];
  const float* bv = (const float*)d_in[9];
  const float* Wp = (const float*)d_in[10];
  const float* ub = (const float*)d_in[11];
  const float* vb = (const float*)d_in[12];
  const float* Wo = (const float*)d_in[13];
  const float* bo = (const float*)d_in[14];
  float* out = (float*)d_out;

  char* ws = (char*)d_ws;
  const size_t MB = 1ull << 20;
  // Layout:
  //   [16,18.5) MB : wb (5x bf16 weights)
  //   [19,23)      : qu   [23,27): qv   [27,31): kk   [31,35): vt
  //   [35,47.7)    : phZ [B*H, 3S+16, 32]
  //   [48,52)      : ctx bf16
  __bf16* wb  = (__bf16*)(ws + 16 * MB);
  __bf16* qu  = (__bf16*)(ws + 19 * MB);
  __bf16* qv  = (__bf16*)(ws + 23 * MB);
  __bf16* kk  = (__bf16*)(ws + 27 * MB);
  __bf16* vt  = (__bf16*)(ws + 31 * MB);
  __bf16* phZ = (__bf16*)(ws + 35 * MB);
  __bf16* ctx = (__bf16*)(ws + 48 * MB);

  conv_kernel<<<dim3(136, 6), dim3(256), 0, stream>>>(
      Wq, Wk, Wv, Wp, Wo, wb, phZ);

  gemm_kernel<0><<<dim3(512), dim3(256), 0, stream>>>(
      query, key, value, pos, wb, ctx, bq, bk, bv, bo, ub, vb,
      qu, qv, kk, vt, phZ, out);

  attn_kernel<<<dim3(1024), dim3(256), 0, stream>>>(
      qu, qv, kk, vt, phZ, ctx);

  gemm_kernel<1><<<dim3(256), dim3(256), 0, stream>>>(
      query, key, value, pos, wb, ctx, bq, bk, bv, bo, ub, vb,
      qu, qv, kk, vt, phZ, out);
}

// Round 20
// 77.284 us; speedup vs baseline: 1.0887x; 1.0887x over previous
//
#include <hip/hip_runtime.h>
#include <hip/hip_bf16.h>
#include <math.h>

// Transformer-XL relative multi-head attention, bf16 MFMA implementation.
// B=4, S=1024, H=16, Dh=32, DIM=512.
//
// relative_shift identity: shifted[q,k] = qv[q]·pA[m] + qv[q+1]·pB[m],
// m = k - q + S - 1;  pA[m]=Z[S+1+m], pB[m]=Z[m] with a single zero-padded
// tensor Z (rows [S+1, 2S+1) = p, all else 0).
//
// Round 20: REVERT to R18 (best: 77.3us). R19's BN=256 experiment regressed
// (-7us): the stall is per-iteration load latency, not barrier count —
// widening the tile lengthened the load burst and halved L2 panel sharing.
// R18 form: gemm BM=64/BN=128, A-staging fused with f32->bf16 cvt
// (reg-staging + swizzled ds_write), B via global_load_lds; attn = R16
// (2-way-free swizzle, Z register reuse, 1 barrier/64k, vmcnt(3), setprio,
// ones-MFMA row sums, max-free exp2 softmax, __shfl diagonal gather).

typedef float f32x4 __attribute__((ext_vector_type(4)));
typedef __bf16 bf16x8 __attribute__((ext_vector_type(8)));
typedef __bf16 bf16x2 __attribute__((ext_vector_type(2)));

#define MFMA16(a, b, c) __builtin_amdgcn_mfma_f32_16x16x32_bf16((a), (b), (c), 0, 0, 0)

constexpr int Bb  = 4;
constexpr int S   = 1024;
constexpr int H   = 16;
constexpr int Dh  = 32;
constexpr int DIM = 512;
// 1/sqrt(32) * log2(e): scores come out pre-scaled for v_exp_f32 (=2^x).
constexpr float SCALEL2E = 0.25501818637084186f;
constexpr int ZROWS = 3 * S + 16;              // phZ rows per (b,h)

constexpr size_t XN = (size_t)Bb * S * DIM;   // elems per activation tensor
constexpr size_t WN = (size_t)DIM * DIM;      // elems per weight matrix

__device__ inline bf16x8 cvt8(const float* __restrict__ p) {
  f32x4 a = *(const f32x4*)p;
  f32x4 b = *(const f32x4*)(p + 4);
  bf16x8 r;
  r[0] = (__bf16)a[0]; r[1] = (__bf16)a[1]; r[2] = (__bf16)a[2]; r[3] = (__bf16)a[3];
  r[4] = (__bf16)b[0]; r[5] = (__bf16)b[1]; r[6] = (__bf16)b[2]; r[7] = (__bf16)b[3];
  return r;
}

__device__ inline float fexp2(float x) {
  float r;
  asm("v_exp_f32 %0, %1" : "=v"(r) : "v"(x));
  return r;
}

__device__ inline void gload_lds16(const __bf16* g, __bf16* l) {
  __builtin_amdgcn_global_load_lds(
      (const __attribute__((address_space(1))) unsigned int*)g,
      (__attribute__((address_space(3))) unsigned int*)l, 16, 0, 0);
}

// ---------------------------------------------------------------------------
// Kernel 0: f32 -> bf16 weight conversion (y=0..4) + phZ zero bands (y=5).
// ---------------------------------------------------------------------------
__global__ __launch_bounds__(256) void conv_kernel(
    const float* __restrict__ wq, const float* __restrict__ wk,
    const float* __restrict__ wv, const float* __restrict__ wp,
    const float* __restrict__ wo,
    __bf16* __restrict__ wb, __bf16* __restrict__ phZ)
{
  const int y = blockIdx.y;
  if (y == 5) {
    // zero only the bands the attn kernel ever reads as zeros:
    // rows [960,1032) and [2040,2104) per bh (p rows overwrite the overlap).
    const int e8 = blockIdx.x * 256 + threadIdx.x;   // grid.x = 136
    if (e8 < 64 * 136 * 4) {
      const int rowIdx = e8 >> 2, chunk = e8 & 3;
      const int bh = rowIdx / 136;
      const int rl = rowIdx - bh * 136;
      const int row = (rl < 72) ? (960 + rl) : (2040 + (rl - 72));
      bf16x8 zz = {};
      *(bf16x8*)(phZ + ((size_t)bh * ZROWS + row) * Dh + chunk * 8) = zz;
    }
    return;
  }
  const float* src = (y == 0) ? wq : (y == 1) ? wk : (y == 2) ? wv
                   : (y == 3) ? wp : wo;
  __bf16* dst = wb + (size_t)y * WN;
  const size_t i = ((size_t)blockIdx.x * 256 + threadIdx.x) * 8;
  if (i >= WN) return;
  *(bf16x8*)(dst + i) = cvt8(src + i);
}

// ---------------------------------------------------------------------------
// Kernel 1: tiled bf16 GEMM  C[M, N=512] = A @ B^T, K=512.
// BM=64 (MR=2), 4 waves, BK=64; B via global_load_lds(16B, XOR-swizzled
// source). MODE 0 (z=0..3 projections, grid 1024): A staged from the f32
// activation inputs with inline cvt (reg-staging + swizzled ds_write_b128).
// MODE 1 (z=4 outproj, grid 256): A = ctx bf16 via global_load_lds.
// z=2 writes k-interleaved V^T via LDS transpose (packed bf16x2 writes +
// coalesced b128 global stores).
// ---------------------------------------------------------------------------
template <int MODE>
__global__ __launch_bounds__(256) void gemm_kernel(
    const float* __restrict__ xq, const float* __restrict__ xk,
    const float* __restrict__ xv, const float* __restrict__ xp,
    const __bf16* __restrict__ wb, const __bf16* __restrict__ ctxp,
    const float* __restrict__ bq, const float* __restrict__ bk,
    const float* __restrict__ bv, const float* __restrict__ bo,
    const float* __restrict__ ub, const float* __restrict__ vb,
    __bf16* __restrict__ qu, __bf16* __restrict__ qv,
    __bf16* __restrict__ kk, __bf16* __restrict__ vt,
    __bf16* __restrict__ phZ,
    float* __restrict__ outp)
{
  constexpr int MR = 2;                       // m-frags per wave
  constexpr int BM = MR * 32;                 // 64-row block M-tile
  __shared__ __align__(16) __bf16 smem[BM * 64 + 128 * 64];
  __bf16* As = smem;                 // [64 x 64]
  __bf16* Bs = smem + BM * 64;       // [128 x 64]
  __bf16* trans = smem;              // z=2 epilogue: [128 d][64 s]

  const int bid = blockIdx.x;
  const int u = bid >> 3;
  const int by = u & 3;
  const int idx = (bid & 7) + 8 * (u >> 2);
  int bx, z;
  if (MODE == 0) { bx = idx & 63; z = idx >> 6; }
  else           { bx = idx;      z = 4; }

  const float* Axf = (z == 0) ? xq : (z == 1) ? xk : (z == 2) ? xv : xp;
  const __bf16* Bg = wb + (size_t)z * WN;

  const int tid = threadIdx.x;
  const int wid = tid >> 6;
  const int ln = tid & 63;
  const int lm = ln & 15, lg = ln >> 4;
  const int wr = wid >> 1, wc = wid & 1;
  const int brow = bx * BM;
  const int bcol = by * 128;

  const int srow = ln >> 3;
  const int sc   = ln & 7;

  f32x4 acc[MR][4] = {};

  for (int kt = 0; kt < DIM / 64; ++kt) {
    const int k0 = kt * 64;
    if (MODE == 0) {
      // A: f32 -> bf16 reg-staging. Wave stages rows [wid*16, wid*16+16);
      // lane: row rl = wid*16 + (ln>>2), chunks (ln&3) and (ln&3)+4.
      const int rl = wid * 16 + (ln >> 2);
      const float* Af = Axf + (size_t)(brow + rl) * DIM + k0;
      const int c0_ = ln & 3;
      const int c1_ = c0_ + 4;
      *(bf16x8*)&As[rl * 64 + ((c0_ ^ (rl & 7)) * 8)] = cvt8(Af + c0_ * 8);
      *(bf16x8*)&As[rl * 64 + ((c1_ ^ (rl & 7)) * 8)] = cvt8(Af + c1_ * 8);
    } else {
#pragma unroll
      for (int i = 0; i < MR; ++i) {          // A: ctx bf16 via gload_lds
        const int rb = wid * (MR * 8) + i * 8;
        const int r = rb + srow;
        const int cg = sc ^ (r & 7);
        gload_lds16(ctxp + (size_t)(brow + r) * DIM + k0 + cg * 8,
                    &As[rb * 64]);
      }
    }
#pragma unroll
    for (int i = 0; i < 4; ++i) {             // B: 128 rows via gload_lds
      const int rb = wid * 32 + i * 8;
      const int r = rb + srow;
      const int cg = sc ^ (r & 7);
      gload_lds16(Bg + (size_t)(bcol + r) * DIM + k0 + cg * 8, &Bs[rb * 64]);
    }
    __syncthreads();

#pragma unroll
    for (int ks = 0; ks < 2; ++ks) {
      bf16x8 a[MR], b[4];
#pragma unroll
      for (int m = 0; m < MR; ++m) {
        const int row = wr * (MR * 16) + m * 16 + lm;
        const int cc = (ks * 4 + lg) ^ (row & 7);
        a[m] = *(const bf16x8*)&As[row * 64 + cc * 8];
      }
#pragma unroll
      for (int n = 0; n < 4; ++n) {
        const int row = wc * 64 + n * 16 + lm;
        const int cc = (ks * 4 + lg) ^ (row & 7);
        b[n] = *(const bf16x8*)&Bs[row * 64 + cc * 8];
      }
#pragma unroll
      for (int m = 0; m < MR; ++m)
#pragma unroll
        for (int n = 0; n < 4; ++n)
          acc[m][n] = MFMA16(a[m], b[n], acc[m][n]);
    }
    __syncthreads();
  }

  // ---- epilogue
  if (MODE == 0 && z == 2) {
    // k-interleaved V^T via LDS transpose (MR=2 form). Each wave owns a
    // 32-s-block (rows wr*32..wr*32+31); pair (s, s+16) = (acc[0][n][r],
    // acc[1][n][r]) with t = lg*4+r -> slots (2t, 2t+1) at p = wr*32 + 2t.
    const int b = brow >> 10;
    const int sbase = brow & (S - 1);
#pragma unroll
    for (int n = 0; n < 4; ++n) {
      const int dl = wc * 64 + n * 16 + lm;          // 0..127
      const float bias = bv[bcol + dl];
#pragma unroll
      for (int r = 0; r < 4; ++r) {
        const int p = wr * 32 + 2 * (lg * 4 + r);    // even slot
        bf16x2 pk;
        pk[0] = (__bf16)(acc[0][n][r] + bias);       // col s
        pk[1] = (__bf16)(acc[1][n][r] + bias);       // col s+16
        const int base = dl * 64 + (((p >> 3) ^ (dl & 7)) * 8) + (p & 7);
        *(bf16x2*)(trans + base) = pk;
      }
    }
    __syncthreads();
#pragma unroll
    for (int j = 0; j < 2; ++j) {
      const int dl = (tid >> 2) + j * 64;            // 0..127
      const int d = dl & 31, hl = dl >> 5;
      const int cp = (tid & 3) * 2;                  // chunk pair (16 elems)
      bf16x8 v0 = *(const bf16x8*)(trans + dl * 64 + ((cp ^ (dl & 7)) * 8));
      bf16x8 v1 = *(const bf16x8*)(trans + dl * 64 + (((cp + 1) ^ (dl & 7)) * 8));
      const int bh2 = b * H + (bcol >> 5) + hl;
      __bf16* dst = vt + ((size_t)bh2 * Dh + d) * S + sbase + cp * 8;
      *(bf16x8*)dst = v0;
      *(bf16x8*)(dst + 8) = v1;
    }
    return;
  }

#pragma unroll
  for (int n = 0; n < 4; ++n) {
    const int o = bcol + wc * 64 + n * 16 + lm;
    float bias = 0.f, ubv = 0.f, vbv = 0.f;
    if (z == 0) { bias = bq[o]; ubv = ub[o]; vbv = vb[o]; }
    else if (z == 1) bias = bk[o];
    else if (z == 4) bias = bo[o];
    const int h = o >> 5, d = o & 31;
#pragma unroll
    for (int m = 0; m < MR; ++m) {
#pragma unroll
      for (int r = 0; r < 4; ++r) {
        const int M = brow + wr * (MR * 16) + m * 16 + lg * 4 + r;
        const float val = acc[m][n][r];
        if (z == 4) {
          outp[(size_t)M * DIM + o] = val + bias;
          continue;
        }
        const int b = M >> 10, s = M & (S - 1);
        const int bh = b * H + h;
        if (z == 0) {
          // 1/sqrt(Dh)*log2(e) folded in (scores feed v_exp_f32 directly).
          const size_t idx2 = ((size_t)bh * S + s) * Dh + d;
          qu[idx2] = (__bf16)((val + bias + ubv) * SCALEL2E);
          qv[idx2] = (__bf16)((val + bias + vbv) * SCALEL2E);
        } else if (z == 1) {
          kk[((size_t)bh * S + s) * Dh + d] = (__bf16)(val + bias);
        } else {
          // phZ rows [S+1, 2S+1) = p; zero bands pre-filled by conv.
          phZ[((size_t)bh * ZROWS + (S + 1 + s)) * Dh + d] = (__bf16)val;
        }
      }
    }
  }
}

// ---------------------------------------------------------------------------
// Kernel 2: fused attention (R16, unchanged). 256-thread blocks, 4 waves x
// 16 q-rows, grid 1024. K/V staged 2 64-k groups ahead in 4 LDS buffers with
// 2-way-free XOR swizzle s(row)=(row>>1)&3; Z windows register-reused (4
// loads/iter); ONE barrier per 64-k with counted vmcnt(3); per-half P
// buffers (packed b32 stores, k-interleaved V^T); setprio around MFMA;
// ones-MFMA row sums; max-free softmax (exp2); pos gather via __shfl.
// ---------------------------------------------------------------------------
__global__ __launch_bounds__(256, 4) void attn_kernel(
    const __bf16* __restrict__ qu, const __bf16* __restrict__ qv,
    const __bf16* __restrict__ kk, const __bf16* __restrict__ vt,
    const __bf16* __restrict__ phZ,
    __bf16* __restrict__ ctx)
{
  __shared__ __align__(16) __bf16 kv_lds[4][2][1024];  // [buf][K|V][32x32]
  __shared__ __align__(16) __bf16 at_all[4][2][16 * 40];

  const int tid = threadIdx.x;
  const int wid = tid >> 6;
  const int l = tid & 63;
  const int lm = l & 15, lg = l >> 4;

  const int bid = blockIdx.x;               // [0, 1024)
  const int bh = (bid & 7) + 8 * ((bid >> 3) & 7);  // bh resident on XCD bid&7
  const int q0 = (bid >> 6) * 64 + wid * 16;
  const int h = bh & (H - 1), b = bh >> 4;

  const __bf16* qub = qu + (size_t)bh * S * Dh;
  const __bf16* qvb = qv + (size_t)bh * S * Dh;
  const __bf16* kb  = kk + (size_t)bh * S * Dh;
  const __bf16* vtb = vt + (size_t)bh * Dh * S;
  const __bf16* pZb = phZ + (size_t)bh * ZROWS * Dh;
  const __bf16* pAb = pZb + (size_t)(S + 1) * Dh;   // pA[m] = Z[S+1+m]

  const bf16x8 au  = *(const bf16x8*)(qub + (size_t)(q0 + lm) * Dh + lg * 8);
  const bf16x8 avA = *(const bf16x8*)(qvb + (size_t)(q0 + lm) * Dh + lg * 8);
  // row q+1 for the pB term; one-past reads hit allocated memory and are
  // multiplied by pB rows that are exactly zero wherever consumed.
  const bf16x8 avB = *(const bf16x8*)(qvb + (size_t)(q0 + 1 + lm) * Dh + lg * 8);

  int  slr[4];
  bool prd[4];
#pragma unroll
  for (int r = 0; r < 4; ++r) {
    const int qr = lg * 4 + r;
    slr[r] = (l & 48) | ((lm - qr + 15) & 15);
    prd[r] = (lm <= qr);
  }

  bf16x8 ones8;
#pragma unroll
  for (int i = 0; i < 8; ++i) ones8[i] = (__bf16)1.0f;

  f32x4 cta = {0.f,0.f,0.f,0.f}, ctb = {0.f,0.f,0.f,0.f};
  f32x4 ls  = {0.f,0.f,0.f,0.f};
  const f32x4 zero4 = {0.f,0.f,0.f,0.f};

  // staging: lane l writes 16B at linear offset l*16 in its wave's 1KB
  // quadrant (rows srow=l>>2, storage chunk l&3). Source chunk inverse-
  // swizzled with s(row) = (row>>1)&3  ->  ((l&3) ^ ((l>>3)&3)).
  const int srow = l >> 2;
  const int scg  = ((l & 3) ^ ((l >> 3) & 3)) * 8;
  auto stage = [&](int kt, int buf) {
    const __bf16* src;
    if (wid == 0)      src = kb  + (size_t)(kt + srow) * Dh + scg;
    else if (wid == 1) src = kb  + (size_t)(kt + 16 + srow) * Dh + scg;
    else if (wid == 2) src = vtb + (size_t)srow * S + kt + scg;
    else               src = vtb + (size_t)(16 + srow) * S + kt + scg;
    gload_lds16(src, &kv_lds[buf][wid >> 1][(wid & 1) * 512]);
  };

  // read chunk, same swizzle: rows lm and lm+16 share s = (lm>>1)&3.
  const int cc = (lg ^ ((lm >> 1) & 3)) * 8;

  // Z-window tile load: window(ktc) tile at +off (16-row tile), base uB_.
  auto zld = [&](int ktc, int off, bool uB_) -> bf16x8 {
    const int mb = ktc - q0 + (S - 16);
    const __bf16* zb = uB_ ? pZb : pAb;
    return *(const bf16x8*)(zb + (size_t)(mb + off + lm) * Dh + lg * 8);
  };

  // One 32-k tile using a resident Z register set.
  auto half = [&](int kt, int tb, __bf16* at,
                  bf16x8 z0, bf16x8 z1, bf16x8 z2, bool uB_) {
    const __bf16* Ks = kv_lds[tb][0];
    const __bf16* Vs = kv_lds[tb][1];
    bf16x8 kf0 = *(const bf16x8*)(Ks + lm * 32 + cc);
    bf16x8 kf1 = *(const bf16x8*)(Ks + (lm + 16) * 32 + cc);
    __builtin_amdgcn_s_setprio(1);
    f32x4 c0 = MFMA16(au, kf0, zero4);
    f32x4 c1 = MFMA16(au, kf1, zero4);
    const bf16x8 av = uB_ ? avB : avA;
    f32x4 pt0 = MFMA16(av, z0, zero4);
    f32x4 pt1 = MFMA16(av, z1, zero4);
    f32x4 pt2 = MFMA16(av, z2, zero4);
    __builtin_amdgcn_s_setprio(0);
    if (uB_ && (kt < q0 + 16)) {  // diagonal band (once per wave): add pA term
      const int mb = kt - q0 + (S - 16);
      bf16x8 y0 = *(const bf16x8*)(pAb + (size_t)(mb + lm) * Dh + lg * 8);
      bf16x8 y1 = *(const bf16x8*)(pAb + (size_t)(mb + 16 + lm) * Dh + lg * 8);
      bf16x8 y2 = *(const bf16x8*)(pAb + (size_t)(mb + 32 + lm) * Dh + lg * 8);
      pt0 = MFMA16(avA, y0, pt0);
      pt1 = MFMA16(avA, y1, pt1);
      pt2 = MFMA16(avA, y2, pt2);
    }

#pragma unroll
    for (int r = 0; r < 4; ++r) {
      const float v0 = __shfl(pt0[r], slr[r], 64);
      const float v1 = __shfl(pt1[r], slr[r], 64);
      const float v2 = __shfl(pt2[r], slr[r], 64);
      const float s0 = c0[r] + (prd[r] ? v0 : v1);
      const float s1 = c1[r] + (prd[r] ? v1 : v2);
      bf16x2 pp;
      pp[0] = (__bf16)fexp2(s0);             // k-col kt+lm     -> slot 2*lm
      pp[1] = (__bf16)fexp2(s1);             // k-col kt+16+lm  -> slot 2*lm+1
      *(bf16x2*)(at + (lg * 4 + r) * 40 + 2 * lm) = pp;
    }

    bf16x8 af  = *(const bf16x8*)(at + lm * 40 + lg * 8);
    bf16x8 vf0 = *(const bf16x8*)(Vs + lm * 32 + cc);
    bf16x8 vf1 = *(const bf16x8*)(Vs + (lm + 16) * 32 + cc);
    __builtin_amdgcn_s_setprio(1);
    cta = MFMA16(af, vf0, cta);
    ctb = MFMA16(af, vf1, ctb);
    ls  = MFMA16(af, ones8, ls);
    __builtin_amdgcn_s_setprio(0);
  };

  __bf16* at0 = at_all[wid][0];
  __bf16* at1 = at_all[wid][1];

  // ---- prologue: Z(0) + stage tiles 0,1.
  bf16x8 zA0, zA1, zA2;
  bool uA = (0 > q0 - 31);
  zA0 = zld(0, 0, uA);
  zA1 = zld(0, 16, uA);
  zA2 = zld(0, 32, uA);
  stage(0, 0);
  stage(32, 1);
  asm volatile("s_waitcnt vmcnt(0)" ::: "memory");
  __builtin_amdgcn_s_barrier();

  for (int kt = 0; kt < S; kt += 64) {
    const int t = kt >> 5;
    // next-64k stages first (oldest in vmcnt order -> full-body slack)
    stage((kt + 64 < S) ? kt + 64 : kt, (t + 2) & 3);
    stage((kt + 96 < S) ? kt + 96 : kt, (t + 3) & 3);

    // zB window (kt+32): tile0 == zA window tile2 when bases match.
    const bool uB = ((kt + 32) > q0 - 31);
    bf16x8 zB0;
    if (uB == uA) zB0 = zA2;
    else          zB0 = zld(kt + 32, 0, uB);
    bf16x8 zB1 = zld(kt + 32, 16, uB);
    bf16x8 zB2 = zld(kt + 32, 32, uB);

    half(kt, t & 3, at0, zA0, zA1, zA2, uA);

    // zA' window (kt+64): tiles 16,32 loaded directly (first use next iter);
    // tile0 == zB2 when bases match (copied after half B).
    const int ktn = (kt + 64 < S) ? kt + 64 : (S - 32);
    const bool uAn = (ktn > q0 - 31);
    zA1 = zld(ktn, 16, uAn);
    zA2 = zld(ktn, 32, uAn);

    half(kt + 32, (t + 1) & 3, at1, zB0, zB1, zB2, uB);

    if (uAn == uB) zA0 = zB2;
    else           zA0 = zld(ktn, 0, uAn);
    uA = uAn;

    asm volatile("s_waitcnt vmcnt(3)" ::: "memory");
    __builtin_amdgcn_s_barrier();
  }

  // ---- normalize + store ctx (ls[r] = row sum, identical across lm lanes)
#pragma unroll
  for (int r = 0; r < 4; ++r) {
    const int s0 = q0 + lg * 4 + r;
    const float inv = 1.f / ls[r];
    __bf16* cp = ctx + ((size_t)b * S + s0) * DIM + h * Dh;
    cp[lm]      = (__bf16)(cta[r] * inv);
    cp[16 + lm] = (__bf16)(ctb[r] * inv);
  }
}

// ---------------------------------------------------------------------------
extern "C" void kernel_launch(void* const* d_in, const int* in_sizes, int n_in,
                              void* d_out, int out_size, void* d_ws, size_t ws_size,
                              hipStream_t stream) {
  const float* query = (const float*)d_in[0];
  const float* key   = (const float*)d_in[1];
  const float* value = (const float*)d_in[2];
  const float* pos   = (const float*)d_in[3];
  const float* Wq = (const float*)d_in[4];
  const float* bq = (const float*)d_in[5];
  const float* Wk = (const float*)d_in[6];
  const float* bk = (const float*)d_in[7];
  const float* Wv = (const float*)d_in[8];
  const float* bv = (const float*)d_in[9];
  const float* Wp = (const float*)d_in[10];
  const float* ub = (const float*)d_in[11];
  const float* vb = (const float*)d_in[12];
  const float* Wo = (const float*)d_in[13];
  const float* bo = (const float*)d_in[14];
  float* out = (float*)d_out;

  char* ws = (char*)d_ws;
  const size_t MB = 1ull << 20;
  // Layout:
  //   [16,18.5) MB : wb (5x bf16 weights)
  //   [19,23)      : qu   [23,27): qv   [27,31): kk   [31,35): vt
  //   [35,47.7)    : phZ [B*H, 3S+16, 32]
  //   [48,52)      : ctx bf16
  __bf16* wb  = (__bf16*)(ws + 16 * MB);
  __bf16* qu  = (__bf16*)(ws + 19 * MB);
  __bf16* qv  = (__bf16*)(ws + 23 * MB);
  __bf16* kk  = (__bf16*)(ws + 27 * MB);
  __bf16* vt  = (__bf16*)(ws + 31 * MB);
  __bf16* phZ = (__bf16*)(ws + 35 * MB);
  __bf16* ctx = (__bf16*)(ws + 48 * MB);

  conv_kernel<<<dim3(136, 6), dim3(256), 0, stream>>>(
      Wq, Wk, Wv, Wp, Wo, wb, phZ);

  gemm_kernel<0><<<dim3(1024), dim3(256), 0, stream>>>(
      query, key, value, pos, wb, ctx, bq, bk, bv, bo, ub, vb,
      qu, qv, kk, vt, phZ, out);

  attn_kernel<<<dim3(1024), dim3(256), 0, stream>>>(
      qu, qv, kk, vt, phZ, ctx);

  gemm_kernel<1><<<dim3(256), dim3(256), 0, stream>>>(
      query, key, value, pos, wb, ctx, bq, bk, bv, bo, ub, vb,
      qu, qv, kk, vt, phZ, out);
}